// Round 1
// baseline (530.334 us; speedup 1.0000x reference)
//
#include <hip/hip_runtime.h>

// DynamicLinearModel: predicted_Y = theta + X@eta + Z@zeta,
// theta[t] = sigmoid(G)*theta[t-1] + (Z[t-1]@gamma), theta[0]=0.
// 3-phase chunked linear scan. See analysis: memory-bound, ~552MB traffic.

constexpr int DIM   = 32;
constexpr int BLOCK = 256;
constexpr int K     = 8;            // consecutive timesteps per thread
constexpr int CHUNK = BLOCK * K;    // 2048 timesteps per block

__device__ __forceinline__ float sigmoidf_(float x) {
    return 1.0f / (1.0f + expf(-x));
}

// ---------------------------------------------------------------------------
// Phase A: compute u[t] = Z[t]·gamma  (to u_ws), v[t] = X[t]·eta + Z[t]·zeta
// (stashed into d_out), and per-chunk scan aggregate (aggA[c], aggB[c]).
// Operator: state s -> a*s + b;  compose(P earlier, Q later) = (aP*aQ, aQ*bP + bQ)
// ---------------------------------------------------------------------------
__global__ __launch_bounds__(BLOCK)
void dlm_phaseA(const float* __restrict__ X,
                const float* __restrict__ Z,
                const float* __restrict__ Gp,
                const float* __restrict__ eta,
                const float* __restrict__ zeta,
                const float* __restrict__ gamma,
                float* __restrict__ v_out,    // = d_out, used as v scratch
                float* __restrict__ u_ws,     // may be null (compact path)
                float* __restrict__ aggA,
                float* __restrict__ aggB,
                int T, int store_u)
{
    const float G = sigmoidf_(Gp[0]);
    const int c   = blockIdx.x;
    const int tid = threadIdx.x;
    const int t0  = c * CHUNK + tid * K;
    const int nval = min(K, max(0, T - t0));

    // fixed 32-vectors: uniform addresses -> scalar loads, broadcast
    const float4* gm = reinterpret_cast<const float4*>(gamma);
    const float4* zt = reinterpret_cast<const float4*>(zeta);
    const float4* et = reinterpret_cast<const float4*>(eta);
    float4 g4[8], s4[8], e4[8];
#pragma unroll
    for (int q = 0; q < 8; ++q) { g4[q] = gm[q]; s4[q] = zt[q]; e4[q] = et[q]; }

    float uu[K], vv[K];
    float a = 1.0f, b = 0.0f;
#pragma unroll
    for (int j = 0; j < K; ++j) {
        uu[j] = 0.0f; vv[j] = 0.0f;
        if (j < nval) {
            const int t = t0 + j;
            const float4* zr = reinterpret_cast<const float4*>(Z + (size_t)t * DIM);
            const float4* xr = reinterpret_cast<const float4*>(X + (size_t)t * DIM);
            float u = 0.0f, v = 0.0f;
#pragma unroll
            for (int q = 0; q < 8; ++q) {
                float4 z = zr[q];
                float4 x = xr[q];
                u += z.x*g4[q].x + z.y*g4[q].y + z.z*g4[q].z + z.w*g4[q].w;
                v += z.x*s4[q].x + z.y*s4[q].y + z.z*s4[q].z + z.w*s4[q].w
                   + x.x*e4[q].x + x.y*e4[q].y + x.z*e4[q].z + x.w*e4[q].w;
            }
            uu[j] = u; vv[j] = v;
            b = G * b + u;   // ordered within-thread scan aggregate
            a *= G;
        }
    }

    // store v (and u on fast path), vectorized when fully in range
    if (nval == K) {
        float4* vp = reinterpret_cast<float4*>(v_out + t0);
        vp[0] = make_float4(vv[0], vv[1], vv[2], vv[3]);
        vp[1] = make_float4(vv[4], vv[5], vv[6], vv[7]);
        if (store_u) {
            float4* up = reinterpret_cast<float4*>(u_ws + t0);
            up[0] = make_float4(uu[0], uu[1], uu[2], uu[3]);
            up[1] = make_float4(uu[4], uu[5], uu[6], uu[7]);
        }
    } else {
        for (int j = 0; j < nval; ++j) {
            v_out[t0 + j] = vv[j];
            if (store_u) u_ws[t0 + j] = uu[j];
        }
    }

    // order-preserving pairwise tree reduction of (a,b) across the block
    __shared__ float as_[BLOCK], bs_[BLOCK];
    as_[tid] = a; bs_[tid] = b;
    __syncthreads();
#pragma unroll
    for (int s = 1; s < BLOCK; s <<= 1) {
        if ((tid & (2 * s - 1)) == 0) {
            float ar = as_[tid + s], br = bs_[tid + s];
            bs_[tid] = ar * bs_[tid] + br;   // compose(left=tid, right=tid+s)
            as_[tid] = as_[tid] * ar;
        }
        __syncthreads();
    }
    if (tid == 0) { aggA[c] = as_[0]; aggB[c] = bs_[0]; }
}

// ---------------------------------------------------------------------------
// Phase B: single block, exclusive scan over chunk aggregates -> carry[c]
// carry[c] = theta-state entering chunk c (initial state is 0, so carry = B_excl)
// ---------------------------------------------------------------------------
__global__ __launch_bounds__(1024)
void dlm_phaseB(const float* __restrict__ aggA,
                const float* __restrict__ aggB,
                float* __restrict__ carry,
                int NC)
{
    __shared__ float as_[1024], bs_[1024];
    const int tid = threadIdx.x;
    float runS = 0.0f;   // state entering current tile
    for (int base = 0; base < NC; base += 1024) {
        const int idx = base + tid;
        float a = 1.0f, b = 0.0f;
        if (idx < NC) { a = aggA[idx]; b = aggB[idx]; }
        as_[tid] = a; bs_[tid] = b;
        __syncthreads();
        // Hillis-Steele inclusive scan with compose(earlier, later)
        for (int d = 1; d < 1024; d <<= 1) {
            float pa = 1.0f, pb = 0.0f;
            if (tid >= d) { pa = as_[tid - d]; pb = bs_[tid - d]; }
            __syncthreads();
            if (tid >= d) {
                bs_[tid] = as_[tid] * pb + bs_[tid];
                as_[tid] = pa * as_[tid];
            }
            __syncthreads();
        }
        if (idx < NC) {
            float Ae = 1.0f, Be = 0.0f;
            if (tid > 0) { Ae = as_[tid - 1]; Be = bs_[tid - 1]; }
            carry[idx] = Ae * runS + Be;
        }
        const float Atile = as_[1023];
        const float Btile = bs_[1023];
        __syncthreads();
        runS = Atile * runS + Btile;
    }
}

// ---------------------------------------------------------------------------
// Phase C: per chunk, intra-block exclusive scan of per-thread aggregates,
// then serial K-step scan per thread; out[t] = theta[t] + v[t].
// Fast path loads u from ws; compact path recomputes u from Z·gamma.
// ---------------------------------------------------------------------------
__global__ __launch_bounds__(BLOCK)
void dlm_phaseC(const float* __restrict__ u_ws,
                const float* __restrict__ Z,
                const float* __restrict__ Gp,
                const float* __restrict__ gamma,
                const float* __restrict__ carry,
                float* __restrict__ out,   // holds v on entry
                int T, int have_u)
{
    const float G = sigmoidf_(Gp[0]);
    const int c   = blockIdx.x;
    const int tid = threadIdx.x;
    const int t0  = c * CHUNK + tid * K;
    const int nval = min(K, max(0, T - t0));

    float uu[K];
    if (have_u) {
        if (nval == K) {
            const float4* up = reinterpret_cast<const float4*>(u_ws + t0);
            float4 u0 = up[0], u1 = up[1];
            uu[0]=u0.x; uu[1]=u0.y; uu[2]=u0.z; uu[3]=u0.w;
            uu[4]=u1.x; uu[5]=u1.y; uu[6]=u1.z; uu[7]=u1.w;
        } else {
            for (int j = 0; j < K; ++j) uu[j] = (j < nval) ? u_ws[t0 + j] : 0.0f;
        }
    } else {
        const float4* gm = reinterpret_cast<const float4*>(gamma);
        float4 g4[8];
#pragma unroll
        for (int q = 0; q < 8; ++q) g4[q] = gm[q];
#pragma unroll
        for (int j = 0; j < K; ++j) {
            uu[j] = 0.0f;
            if (j < nval) {
                const float4* zr = reinterpret_cast<const float4*>(Z + (size_t)(t0 + j) * DIM);
                float u = 0.0f;
#pragma unroll
                for (int q = 0; q < 8; ++q) {
                    float4 z = zr[q];
                    u += z.x*g4[q].x + z.y*g4[q].y + z.z*g4[q].z + z.w*g4[q].w;
                }
                uu[j] = u;
            }
        }
    }

    float a = 1.0f, b = 0.0f;
#pragma unroll
    for (int j = 0; j < K; ++j) {
        if (j < nval) { b = G * b + uu[j]; a *= G; }
    }

    __shared__ float as_[BLOCK], bs_[BLOCK];
    as_[tid] = a; bs_[tid] = b;
    __syncthreads();
#pragma unroll
    for (int d = 1; d < BLOCK; d <<= 1) {
        float pa = 1.0f, pb = 0.0f;
        if (tid >= d) { pa = as_[tid - d]; pb = bs_[tid - d]; }
        __syncthreads();
        if (tid >= d) {
            bs_[tid] = as_[tid] * pb + bs_[tid];
            as_[tid] = pa * as_[tid];
        }
        __syncthreads();
    }
    float Ae = 1.0f, Be = 0.0f;
    if (tid > 0) { Ae = as_[tid - 1]; Be = bs_[tid - 1]; }
    float s = Ae * carry[c] + Be;   // theta-state entering this thread's segment

    if (nval == K) {
        float4* op = reinterpret_cast<float4*>(out + t0);
        float4 v0 = op[0], v1 = op[1];
        float r[K];
        const float vj[K] = { v0.x, v0.y, v0.z, v0.w, v1.x, v1.y, v1.z, v1.w };
#pragma unroll
        for (int j = 0; j < K; ++j) {
            r[j] = s + vj[j];        // theta[t] = s, out = theta + v
            s = G * s + uu[j];       // advance state with u[t]
        }
        op[0] = make_float4(r[0], r[1], r[2], r[3]);
        op[1] = make_float4(r[4], r[5], r[6], r[7]);
    } else {
        for (int j = 0; j < nval; ++j) {
            const int t = t0 + j;
            const float v = out[t];
            out[t] = s + v;
            s = G * s + uu[j];
        }
    }
}

// ---------------------------------------------------------------------------
extern "C" void kernel_launch(void* const* d_in, const int* in_sizes, int n_in,
                              void* d_out, int out_size, void* d_ws, size_t ws_size,
                              hipStream_t stream)
{
    const float* X     = (const float*)d_in[0];
    const float* Z     = (const float*)d_in[1];
    const float* Gp    = (const float*)d_in[2];
    const float* eta   = (const float*)d_in[3];
    const float* zeta  = (const float*)d_in[4];
    const float* gamma = (const float*)d_in[5];
    float* out = (float*)d_out;

    const int T  = out_size;                 // 2,000,000
    const int NC = (T + CHUNK - 1) / CHUNK;  // 977 chunks

    // workspace layout: [ u (T, fast path only) | aggA (NC) | aggB (NC) | carry (NC) ]
    const size_t Tpad = ((size_t)T + 3) & ~(size_t)3;
    const size_t need_fast = (Tpad + 3 * (size_t)NC) * sizeof(float);
    const int store_u = (ws_size >= need_fast) ? 1 : 0;   // ws_size is call-invariant

    float* u_ws;
    float* aggA;
    if (store_u) {
        u_ws = (float*)d_ws;
        aggA = u_ws + Tpad;
    } else {
        u_ws = (float*)d_ws;   // unused
        aggA = (float*)d_ws;
    }
    float* aggB  = aggA + NC;
    float* carry = aggB + NC;

    dlm_phaseA<<<NC, BLOCK, 0, stream>>>(X, Z, Gp, eta, zeta, gamma,
                                         out, u_ws, aggA, aggB, T, store_u);
    dlm_phaseB<<<1, 1024, 0, stream>>>(aggA, aggB, carry, NC);
    dlm_phaseC<<<NC, BLOCK, 0, stream>>>(u_ws, Z, Gp, gamma, carry,
                                         out, T, store_u);
}

// Round 3
// 510.901 us; speedup vs baseline: 1.0380x; 1.0380x over previous
//
#include <hip/hip_runtime.h>

// DynamicLinearModel: predicted_Y = theta + X@eta + Z@zeta,
// theta[t] = sigmoid(G)*theta[t-1] + (Z[t-1]@gamma), theta[0]=0.
// 3-phase chunked linear scan, fully-coalesced cooperative layout:
//   8 lanes per row (lane p holds float4 chunk p) -> wave covers 1024B contiguous.
// Tile = 64 rows. Wave owns NT=4 consecutive tiles, block = 4 waves = 16 tiles.

constexpr int DIM   = 32;
constexpr int BLOCK = 256;
constexpr int NWAVE = 4;
constexpr int NT    = 4;               // 64-row tiles per wave
constexpr int TPB   = NWAVE * NT;      // tiles per block

__device__ __forceinline__ float powi_(const float gp[7], int e) {
    // gp[b] = G^(2^b); returns G^e, e in [0,64]
    float r = 1.0f;
#pragma unroll
    for (int b = 0; b < 7; ++b) if (e & (1 << b)) r *= gp[b];
    return r;
}

__device__ __forceinline__ float wsum64_(float x) {
#pragma unroll
    for (int d = 1; d < 64; d <<= 1) x += __shfl_xor(x, d, 64);
    return x;
}

// ---------------------------------------------------------------------------
// Phase A: u[t]=Z[t]·gamma -> u_ws ; v[t]=X[t]·eta+Z[t]·zeta -> d_out ;
// per-block scan aggregate (A,B) with  state -> A*state + B.
// ---------------------------------------------------------------------------
__global__ __launch_bounds__(BLOCK)
void dlm_phaseA(const float* __restrict__ X, const float* __restrict__ Z,
                const float* __restrict__ Gp, const float* __restrict__ eta,
                const float* __restrict__ zeta, const float* __restrict__ gamma,
                float* __restrict__ v_out, float* __restrict__ u_ws,
                float* __restrict__ aggA, float* __restrict__ aggB,
                int T, int tot_tiles, int store_u)
{
    const int tid  = threadIdx.x;
    const int lane = tid & 63;
    const int w    = tid >> 6;
    const int r    = lane >> 3, p = lane & 7;

    const float G = 1.0f / (1.0f + expf(-Gp[0]));
    float gp[7]; gp[0] = G;
#pragma unroll
    for (int b = 1; b < 7; ++b) gp[b] = gp[b-1] * gp[b-1];
    const float g64 = gp[6];
    const float wp  = powi_(gp, 63 - lane);     // G^(63-lane)

    const float4 g4  = reinterpret_cast<const float4*>(gamma)[p];
    const float4 zt4 = reinterpret_cast<const float4*>(zeta)[p];
    const float4 et4 = reinterpret_cast<const float4*>(eta)[p];

    const int tile0 = (blockIdx.x * NWAVE + w) * NT;
    const int ntl   = max(0, min(NT, tot_tiles - tile0));

    const int src = ((lane & 7) << 3) | (lane >> 3);   // transpose source lane

    float aw = 1.0f, bw = 0.0f;
    for (int tI = 0; tI < ntl; ++tI) {
        const int tbase = (tile0 + tI) << 6;
        const int valid = min(64, T - tbase);
        float ku = 0.0f, kv = 0.0f;
#pragma unroll
        for (int i = 0; i < 8; ++i) {
            const int row = tbase + i * 8 + r;
            float pu = 0.0f, pv = 0.0f;
            if (row < T) {
                const float4 z = reinterpret_cast<const float4*>(Z + (size_t)row * DIM)[p];
                const float4 x = reinterpret_cast<const float4*>(X + (size_t)row * DIM)[p];
                pu = z.x*g4.x + z.y*g4.y + z.z*g4.z + z.w*g4.w;
                pv = z.x*zt4.x + z.y*zt4.y + z.z*zt4.z + z.w*zt4.w
                   + x.x*et4.x + x.y*et4.y + x.z*et4.z + x.w*et4.w;
            }
#pragma unroll
            for (int d = 1; d < 8; d <<= 1) {
                pu += __shfl_xor(pu, d, 64);
                pv += __shfl_xor(pv, d, 64);
            }
            if (i == p) { ku = pu; kv = pv; }
        }
        // transpose: lane l <- value of row tbase+l (held by lane (p<<3)|r)
        const float tu = __shfl(ku, src, 64);
        const float tv = __shfl(kv, src, 64);
        if (lane < valid) {
            v_out[tbase + lane] = tv;
            if (store_u) u_ws[tbase + lane] = tu;
        }
        float wt, atile;
        if (valid == 64) { wt = wp; atile = g64; }
        else { wt = (lane < valid) ? powi_(gp, valid - 1 - lane) : 0.0f;
               atile = powi_(gp, valid); }
        const float btile = wsum64_(wt * tu);
        bw = atile * bw + btile;
        aw *= atile;
    }

    __shared__ float As[NWAVE], Bs[NWAVE];
    if (lane == 0) { As[w] = aw; Bs[w] = bw; }
    __syncthreads();
    if (tid == 0) {
        float A = As[0], B = Bs[0];
#pragma unroll
        for (int q = 1; q < NWAVE; ++q) { B = As[q] * B + Bs[q]; A *= As[q]; }
        aggA[blockIdx.x] = A; aggB[blockIdx.x] = B;
    }
}

// ---------------------------------------------------------------------------
// Phase B: single block, exclusive scan over block aggregates -> carry[c]
// ---------------------------------------------------------------------------
__global__ __launch_bounds__(1024)
void dlm_phaseB(const float* __restrict__ aggA,
                const float* __restrict__ aggB,
                float* __restrict__ carry,
                int NC)
{
    __shared__ float as_[1024], bs_[1024];
    const int tid = threadIdx.x;
    float runS = 0.0f;
    for (int base = 0; base < NC; base += 1024) {
        const int idx = base + tid;
        float a = 1.0f, b = 0.0f;
        if (idx < NC) { a = aggA[idx]; b = aggB[idx]; }
        as_[tid] = a; bs_[tid] = b;
        __syncthreads();
        for (int d = 1; d < 1024; d <<= 1) {
            float pa = 1.0f, pb = 0.0f;
            if (tid >= d) { pa = as_[tid - d]; pb = bs_[tid - d]; }
            __syncthreads();
            if (tid >= d) {
                bs_[tid] = as_[tid] * pb + bs_[tid];
                as_[tid] = pa * as_[tid];
            }
            __syncthreads();
        }
        if (idx < NC) {
            float Ae = 1.0f, Be = 0.0f;
            if (tid > 0) { Ae = as_[tid - 1]; Be = bs_[tid - 1]; }
            carry[idx] = Ae * runS + Be;
        }
        const float Atile = as_[1023];
        const float Btile = bs_[1023];
        __syncthreads();
        runS = Atile * runS + Btile;
    }
}

// ---------------------------------------------------------------------------
// Phase C: recompute per-wave aggregates from u (registers), compose with
// carry, then 64-lane Hillis-Steele compose-scan per tile; out = theta + v.
// ---------------------------------------------------------------------------
__global__ __launch_bounds__(BLOCK)
void dlm_phaseC(const float* __restrict__ u_ws, const float* __restrict__ Z,
                const float* __restrict__ Gp, const float* __restrict__ gamma,
                const float* __restrict__ carry, float* __restrict__ out,
                int T, int tot_tiles, int have_u)
{
    const int tid  = threadIdx.x;
    const int lane = tid & 63;
    const int w    = tid >> 6;
    const int r    = lane >> 3, p = lane & 7;

    const float G = 1.0f / (1.0f + expf(-Gp[0]));
    float gp[7]; gp[0] = G;
#pragma unroll
    for (int b = 1; b < 7; ++b) gp[b] = gp[b-1] * gp[b-1];
    const float g64 = gp[6];
    const float wp  = powi_(gp, 63 - lane);

    const int tile0 = (blockIdx.x * NWAVE + w) * NT;
    const int ntl   = max(0, min(NT, tot_tiles - tile0));
    const int src   = ((lane & 7) << 3) | (lane >> 3);

    float u_reg[NT];
    float aw = 1.0f, bw = 0.0f;
#pragma unroll
    for (int tI = 0; tI < NT; ++tI) {
        u_reg[tI] = 0.0f;
        if (tI < ntl) {
            const int tbase = (tile0 + tI) << 6;
            const int valid = min(64, T - tbase);
            float tu;
            if (have_u) {
                tu = (lane < valid) ? u_ws[tbase + lane] : 0.0f;
            } else {
                const float4 g4 = reinterpret_cast<const float4*>(gamma)[p];
                float ku = 0.0f;
#pragma unroll
                for (int i = 0; i < 8; ++i) {
                    const int row = tbase + i * 8 + r;
                    float pu = 0.0f;
                    if (row < T) {
                        const float4 z = reinterpret_cast<const float4*>(Z + (size_t)row * DIM)[p];
                        pu = z.x*g4.x + z.y*g4.y + z.z*g4.z + z.w*g4.w;
                    }
#pragma unroll
                    for (int d = 1; d < 8; d <<= 1) pu += __shfl_xor(pu, d, 64);
                    if (i == p) ku = pu;
                }
                tu = __shfl(ku, src, 64);
                if (lane >= valid) tu = 0.0f;
            }
            u_reg[tI] = tu;
            float wt, atile;
            if (valid == 64) { wt = wp; atile = g64; }
            else { wt = (lane < valid) ? powi_(gp, valid - 1 - lane) : 0.0f;
                   atile = powi_(gp, valid); }
            bw = atile * bw + wsum64_(wt * tu);
            aw *= atile;
        }
    }

    __shared__ float As[NWAVE], Bs[NWAVE];
    if (lane == 0) { As[w] = aw; Bs[w] = bw; }
    __syncthreads();
    float s = carry[blockIdx.x];
    for (int q = 0; q < w; ++q) s = As[q] * s + Bs[q];

#pragma unroll
    for (int tI = 0; tI < NT; ++tI) {
        if (tI < ntl) {
            const int tbase = (tile0 + tI) << 6;
            const int valid = min(64, T - tbase);
            float A = G, B = u_reg[tI];
#pragma unroll
            for (int d = 1; d < 64; d <<= 1) {
                const float Ap = __shfl_up(A, d, 64);
                const float Bp = __shfl_up(B, d, 64);
                if (lane >= d) { B = A * Bp + B; A = A * Ap; }
            }
            const float Ax = __shfl_up(A, 1, 64);
            const float Bx = __shfl_up(B, 1, 64);
            const float theta = (lane == 0) ? s : (Ax * s + Bx);
            if (lane < valid) out[tbase + lane] = theta + out[tbase + lane];
            const float A63 = __shfl(A, 63, 64);
            const float B63 = __shfl(B, 63, 64);
            s = A63 * s + B63;
        }
    }
}

// ---------------------------------------------------------------------------
extern "C" void kernel_launch(void* const* d_in, const int* in_sizes, int n_in,
                              void* d_out, int out_size, void* d_ws, size_t ws_size,
                              hipStream_t stream)
{
    const float* X     = (const float*)d_in[0];
    const float* Z     = (const float*)d_in[1];
    const float* Gp    = (const float*)d_in[2];
    const float* eta   = (const float*)d_in[3];
    const float* zeta  = (const float*)d_in[4];
    const float* gamma = (const float*)d_in[5];
    float* out = (float*)d_out;

    const int T     = out_size;                  // 2,000,000
    const int tiles = (T + 63) >> 6;             // 31250 (64-row tiles)
    const int NC    = (tiles + TPB - 1) / TPB;   // 1954 blocks

    // ws layout: [ u (Tpad, fast path) | aggA (NC) | aggB (NC) | carry (NC) ]
    const size_t Tpad = ((size_t)T + 3) & ~(size_t)3;
    const size_t need = (Tpad + 3 * (size_t)NC) * sizeof(float);
    const int store_u = (ws_size >= need) ? 1 : 0;   // call-invariant

    float* u_ws  = (float*)d_ws;
    float* aggA  = store_u ? (u_ws + Tpad) : (float*)d_ws;
    float* aggB  = aggA + NC;
    float* carry = aggB + NC;

    dlm_phaseA<<<NC, BLOCK, 0, stream>>>(X, Z, Gp, eta, zeta, gamma,
                                         out, u_ws, aggA, aggB, T, tiles, store_u);
    dlm_phaseB<<<1, 1024, 0, stream>>>(aggA, aggB, carry, NC);
    dlm_phaseC<<<NC, BLOCK, 0, stream>>>(u_ws, Z, Gp, gamma, carry,
                                         out, T, tiles, store_u);
}